// Round 1
// baseline (9809.669 us; speedup 1.0000x reference)
//
#include <hip/hip_runtime.h>
#include <math.h>

// Problem constants
#define NWG    48       // workgroups = 768/EC ; all co-resident (<=256 CUs)
#define TT     1024     // timesteps per layer
#define BSZ    16       // batch
#define DHH    768      // hidden dim
#define NGG    4        // gates
#define EC     16       // e-chunk per WG
#define LDR    776      // padded K-row length (bf16 elems); 776*2=1552 B, 16B-aligned, banks offset by 4/row
#define GPITCH 17       // gates_lds pitch to avoid bank conflicts

typedef __attribute__((ext_vector_type(8))) short bf16x8_t;  // 8 bf16 (4 VGPRs) - MFMA A/B frag
typedef __attribute__((ext_vector_type(4))) float f32x4_t;   // MFMA C/D frag

__device__ __forceinline__ unsigned short f2bf(float f) {
  union { float f; unsigned int u; } v; v.f = f;
  return (unsigned short)((v.u + 0x7fffu + ((v.u >> 16) & 1u)) >> 16);  // RNE
}

__global__ void lstm_init_ws(int* cnt) {
  if (threadIdx.x == 0) *cnt = 0;
}

__global__ __launch_bounds__(256, 1) void lstm_persistent(
    const float* __restrict__ states,
    const float* __restrict__ Wx0, const float* __restrict__ R0, const float* __restrict__ b0,
    const float* __restrict__ Wx1, const float* __restrict__ R1, const float* __restrict__ b1,
    float* __restrict__ out, int* __restrict__ cnt, unsigned short* __restrict__ hbuf)
{
  extern __shared__ unsigned char smem[];
  unsigned short* h_lds     = (unsigned short*)smem;            // [BSZ][LDR] bf16, A-operand staging
  unsigned short* r_lds     = h_lds + BSZ * LDR;                // [NGG][EC][LDR] bf16, B-operand (e-major, k contiguous)
  float*          gates_lds = (float*)(r_lds + NGG * EC * LDR); // [NGG][BSZ][GPITCH]
  float*          c_lds     = gates_lds + NGG * BSZ * GPITCH;   // [BSZ][EC] cell state (fp32, persistent)
  float*          b_lds     = c_lds + BSZ * EC;                 // [NGG][EC]

  const int tid  = threadIdx.x;
  const int lane = tid & 63;
  const int wv   = tid >> 6;    // wave id == gate id
  const int bb   = tid >> 4;    // batch row for staging/elementwise (256 = 16*16)
  const int el   = tid & 15;    // local e
  const int e0   = blockIdx.x * EC;
  const int m    = lane & 15;   // MFMA: A-row / B-col / D-col
  const int q    = lane >> 4;   // MFMA quad

  // ---- init: cell state from states[0,1], h0 broadcast (bf16) from states[0,0]
  c_lds[bb * EC + el] = states[(BSZ + bb) * DHH + e0 + el];
  hbuf[bb * DHH + e0 + el] = f2bf(states[bb * DHH + e0 + el]);

  int target = NWG;
  __syncthreads();  // drains vmem (waitcnt vmcnt(0)) before barrier
  if (tid == 0) {
    __hip_atomic_fetch_add(cnt, 1, __ATOMIC_RELEASE, __HIP_MEMORY_SCOPE_AGENT);
    while (__hip_atomic_load(cnt, __ATOMIC_RELAXED, __HIP_MEMORY_SCOPE_AGENT) < target)
      __builtin_amdgcn_s_sleep(4);
    __builtin_amdgcn_fence(__ATOMIC_ACQUIRE, "agent");  // invalidate stale L1/L2 lines
  }
  __syncthreads();

  for (int layer = 0; layer < 2; ++layer) {
    const float* Wx = layer ? Wx1 : Wx0;
    const float* Rm = layer ? R1  : R0;
    const float* bv = layer ? b1  : b0;

    // Stage R chunk into LDS, transposed to B-frag layout: r_lds[g][n][k=d] = R[g][d][e0+n]
    for (int i = tid; i < NGG * DHH; i += 256) {
      const int g = i / DHH, d = i - g * DHH;
      const float* src = Rm + (g * DHH + d) * DHH + e0;
      #pragma unroll
      for (int n = 0; n < EC; ++n)
        r_lds[(g * EC + n) * LDR + d] = f2bf(src[n]);
    }
    if (tid < NGG * EC) b_lds[tid] = bv[(tid >> 4) * DHH + e0 + (tid & 15)];
    __syncthreads();

    for (int t = 0; t < TT; ++t) {
      const int gs = layer * TT + t;
      const unsigned short* __restrict__ hsrc = hbuf + (gs & 1) * (BSZ * DHH);
      unsigned short* __restrict__ hdst = hbuf + ((gs + 1) & 1) * (BSZ * DHH);

      // Wx prefetch for this step (4 gate values per thread); latency hidden behind staging+MFMA
      const float* wxp = Wx + ((bb * TT + t) * NGG) * DHH + e0 + el;
      const float wxv0 = wxp[0];
      const float wxv1 = wxp[DHH];
      const float wxv2 = wxp[2 * DHH];
      const float wxv3 = wxp[3 * DHH];

      // Stage h (bf16) -> LDS, padded rows. 96 x 16B chunks per row, 16 threads/row x 6 chunks.
      {
        const uint4* src = (const uint4*)(hsrc + bb * DHH);
        uint4* dst = (uint4*)(h_lds + bb * LDR);
        #pragma unroll
        for (int j = 0; j < 6; ++j) dst[el + 16 * j] = src[el + 16 * j];
      }
      __syncthreads();

      // MFMA: wave wv computes gate wv's [16b x 16e] tile, K=768
      {
        const unsigned short* ha = h_lds + m * LDR + q * 8;                 // A[m][k]: k = q*8+j
        const unsigned short* rb = r_lds + (wv * EC + m) * LDR + q * 8;     // B[k][n=m]: k = q*8+j
        f32x4_t acc = {0.f, 0.f, 0.f, 0.f};
        #pragma unroll
        for (int k0 = 0; k0 < DHH; k0 += 32) {
          bf16x8_t av  = *(const bf16x8_t*)(ha + k0);
          bf16x8_t bvv = *(const bf16x8_t*)(rb + k0);
          acc = __builtin_amdgcn_mfma_f32_16x16x32_bf16(av, bvv, acc, 0, 0, 0);
        }
        // D layout: row = q*4+r (batch), col = m (e)
        #pragma unroll
        for (int r = 0; r < 4; ++r)
          gates_lds[(wv * BSZ + q * 4 + r) * GPITCH + m] = acc[r];
      }
      __syncthreads();

      // Elementwise LSTM update: one (b, e) per thread
      {
        const float gi = gates_lds[(0 * BSZ + bb) * GPITCH + el] + wxv0 + b_lds[0 * EC + el];
        const float gf = gates_lds[(1 * BSZ + bb) * GPITCH + el] + wxv1 + b_lds[1 * EC + el];
        const float gz = gates_lds[(2 * BSZ + bb) * GPITCH + el] + wxv2 + b_lds[2 * EC + el];
        const float go = gates_lds[(3 * BSZ + bb) * GPITCH + el] + wxv3 + b_lds[3 * EC + el];
        const float iv = 1.f / (1.f + __expf(-gi));
        const float fv = 1.f / (1.f + __expf(-gf));
        const float zv = tanhf(gz);
        const float ov = 1.f / (1.f + __expf(-go));
        const float cold = c_lds[bb * EC + el];
        const float cnew = fv * cold + iv * zv;
        const float hnew = ov * tanhf(cnew);
        c_lds[bb * EC + el] = cnew;
        hdst[bb * DHH + e0 + el] = f2bf(hnew);
        if (layer == 1) {
          out[((t * 2 + 0) * BSZ + bb) * DHH + e0 + el] = hnew;
          out[((t * 2 + 1) * BSZ + bb) * DHH + e0 + el] = cnew;
          if (t == TT - 1) {
            const int HS = TT * 2 * BSZ * DHH;   // 25165824
            out[HS + (0 * BSZ + bb) * DHH + e0 + el] = hnew;               // last_h
            out[HS + (1 * BSZ + bb) * DHH + e0 + el] = cnew;
            out[HS + 2 * BSZ * DHH + (0 * BSZ + bb) * DHH + e0 + el] = hnew; // out (duplicate)
            out[HS + 2 * BSZ * DHH + (1 * BSZ + bb) * DHH + e0 + el] = cnew;
          }
        }
      }

      // Inter-WG barrier: syncthreads drains this WG's stores into L2; the release
      // fetch_add flushes L2 to the coherent point (one buffer_wbl2 per WG-step);
      // acquire fence invalidates stale lines before next step's hbuf reads.
      target += NWG;
      __syncthreads();
      if (tid == 0) {
        __hip_atomic_fetch_add(cnt, 1, __ATOMIC_RELEASE, __HIP_MEMORY_SCOPE_AGENT);
        while (__hip_atomic_load(cnt, __ATOMIC_RELAXED, __HIP_MEMORY_SCOPE_AGENT) < target)
          __builtin_amdgcn_s_sleep(4);
        __builtin_amdgcn_fence(__ATOMIC_ACQUIRE, "agent");
      }
      __syncthreads();
    }
  }
}

extern "C" void kernel_launch(void* const* d_in, const int* in_sizes, int n_in,
                              void* d_out, int out_size, void* d_ws, size_t ws_size,
                              hipStream_t stream) {
  const float* states = (const float*)d_in[0];
  const float* Wx0    = (const float*)d_in[1];
  const float* R0     = (const float*)d_in[2];
  const float* b0     = (const float*)d_in[3];
  const float* Wx1    = (const float*)d_in[4];
  const float* R1     = (const float*)d_in[5];
  const float* b1     = (const float*)d_in[6];
  float* out = (float*)d_out;

  int* cnt = (int*)d_ws;
  unsigned short* hbuf = (unsigned short*)((char*)d_ws + 256);  // [2][16*768] bf16

  const int smem_bytes = (BSZ * LDR + NGG * EC * LDR) * 2 +
                         (NGG * BSZ * GPITCH + BSZ * EC + NGG * EC) * 4;  // 129792 B

  static bool attr_set = false;  // idempotent host-side attribute; same work every call
  if (!attr_set) {
    hipFuncSetAttribute((const void*)lstm_persistent,
                        hipFuncAttributeMaxDynamicSharedMemorySize, smem_bytes);
    attr_set = true;
  }

  lstm_init_ws<<<dim3(1), dim3(64), 0, stream>>>(cnt);
  lstm_persistent<<<dim3(NWG), dim3(256), smem_bytes, stream>>>(
      states, Wx0, R0, b0, Wx1, R1, b1, out, cnt, hbuf);
}